// Round 4
// baseline (69.040 us; speedup 1.0000x reference)
//
#include <hip/hip_runtime.h>
#include <hip/hip_bf16.h>
#include <stdint.h>

#define B_ 2
#define L_ 2048
#define C_ 16
#define D_ 64
#define H_ 64
#define QBLK 128
#define KVBLK 64
#define NTILES 32            // L_/KVBLK
#define NTHREADS 256         // 4 waves, each owns 32 q-rows
#define NHEADS 32            // B_*C_
#define TILE_ELEMS 4096      // KVBLK*64 bf16 elements (8KB)
#define TENSOR_ELEMS (NHEADS * NTILES * TILE_ELEMS)  // 4,194,304

typedef __attribute__((ext_vector_type(8))) short bf16x8;
typedef __attribute__((ext_vector_type(16))) float f32x16;
typedef __attribute__((ext_vector_type(8))) unsigned short u16x8;

__device__ inline unsigned short f2bf(float f) {
  union { float f; unsigned int u; } v; v.f = f;
  unsigned int u = v.u;
  unsigned int r = (u + 0x7FFFu + ((u >> 16) & 1u)) >> 16;  // RNE
  return (unsigned short)r;
}

__device__ inline float fast_exp2(float x) {
#if __has_builtin(__builtin_amdgcn_exp2f)
  return __builtin_amdgcn_exp2f(x);
#else
  return exp2f(x);
#endif
}

__device__ inline void gload_lds16(const unsigned short* g, unsigned short* l) {
  __builtin_amdgcn_global_load_lds(
      (const __attribute__((address_space(1))) unsigned int*)g,
      (__attribute__((address_space(3))) unsigned int*)l, 16, 0, 0);
}

__device__ inline unsigned cvt_pk_bf16(float lo, float hi) {
  unsigned r;
  asm("v_cvt_pk_bf16_f32 %0, %1, %2" : "=v"(r) : "v"(lo), "v"(hi));
  return r;
}

__device__ inline void pl32swap(unsigned &x, unsigned &y) {
#if __has_builtin(__builtin_amdgcn_permlane32_swap)
  auto r = __builtin_amdgcn_permlane32_swap(x, y, false, false);
  x = r[0]; y = r[1];
#else
  asm("v_permlane32_swap_b32 %0, %1" : "+v"(x), "+&v"(y));
#endif
}

__device__ inline float xmax32(float v) {
  unsigned x = __float_as_uint(v), y = x;
  pl32swap(x, y);
  return fmaxf(__uint_as_float(x), __uint_as_float(y));
}

__device__ inline float xsum32(float v) {
  unsigned x = __float_as_uint(v), y = x;
  pl32swap(x, y);
  return __uint_as_float(x) + __uint_as_float(y);
}

// slot swizzle: spreads row&7 AND bit3 so rows 8 apart are 4 slots apart
#define SLOT(grp, row) ((grp) ^ ((row) & 7) ^ (((row) & 8) >> 1))

// ---------------- pre-pass: fp32 -> bf16, pre-transposed + pre-swizzled ----
__global__ __launch_bounds__(256) void prepack_kernel(
    const float* __restrict__ Kg, const float* __restrict__ Vg,
    unsigned short* __restrict__ Kb, unsigned short* __restrict__ Vb) {
  int idx = blockIdx.x * 256 + threadIdx.x;     // 0 .. 2*524288-1
  if (idx < 524288) {
    int i = idx;
    int grp = i & 7, row = (i >> 3) & 63, t = (i >> 9) & 31, head = i >> 14;
    int b = head >> 4, c = head & 15;
    const float* src = Kg + ((size_t)(b * L_ + t * 64 + row) * C_ + c) * D_ + grp * 8;
    float4 a0 = ((const float4*)src)[0];
    float4 a1 = ((const float4*)src)[1];
    u16x8 pk;
    pk[0] = f2bf(a0.x); pk[1] = f2bf(a0.y); pk[2] = f2bf(a0.z); pk[3] = f2bf(a0.w);
    pk[4] = f2bf(a1.x); pk[5] = f2bf(a1.y); pk[6] = f2bf(a1.z); pk[7] = f2bf(a1.w);
    size_t dst = ((size_t)(head * 32 + t) * 64 + row) * 64 + SLOT(grp, row) * 8;
    *(u16x8*)&Kb[dst] = pk;
  } else {
    int i = idx - 524288;
    int h = i & 63, grp = (i >> 6) & 7, t = (i >> 9) & 31, head = i >> 14;
    int b = head >> 4, c = head & 15;
    const float* src = Vg + ((size_t)(b * L_ + t * 64 + grp * 8) * C_ + c) * H_ + h;
    u16x8 pv;
#pragma unroll
    for (int j = 0; j < 8; ++j) pv[j] = f2bf(src[(size_t)j * C_ * H_]);
    size_t dst = ((size_t)(head * 32 + t) * 64 + h) * 64 + SLOT(grp, h) * 8;
    *(u16x8*)&Vb[dst] = pv;
  }
}

// ---------------- flash-attention forward, 32x32 MFMA, swapped QK^T --------
__global__ __launch_bounds__(NTHREADS, 2) void attn_fwd_kernel(
    const float* __restrict__ Qg,
    const unsigned short* __restrict__ Kb,
    const unsigned short* __restrict__ Vb,
    float* __restrict__ Og) {
  __shared__ unsigned short Ks2[3][TILE_ELEMS];  // 24 KB (triple-buffered K)
  __shared__ unsigned short Vt2[3][TILE_ELEMS];  // 24 KB (triple-buffered V^T)

  const int tid  = threadIdx.x;
  const int lane = tid & 63;
  const int w    = tid >> 6;      // wave 0..3, owns q-rows w*32..+31
  const int ql   = lane & 31;     // this lane's q-row within wave
  const int u    = lane >> 5;     // k-chunk selector

  const int bid   = blockIdx.x;
  const int swz   = (bid & 7) * 64 + (bid >> 3);   // XCD-contiguous
  const int head  = swz >> 4;
  const int qtile = swz & 15;
  const int b     = head >> 4;
  const int c     = head & 15;
  const int q0    = qtile * QBLK;

  const unsigned short* KbH = Kb + (size_t)head * NTILES * TILE_ELEMS;
  const unsigned short* VbH = Vb + (size_t)head * NTILES * TILE_ELEMS;

  // Q as B-operand: col = ql (q-row), k = ks*16 + u*8 + j
  const int qr = q0 + w * 32 + ql;
  const float* qrow = Qg + ((size_t)(b * L_ + qr) * C_ + c) * D_;
  bf16x8 qf[4];
#pragma unroll
  for (int ks = 0; ks < 4; ++ks) {
    float4 a0 = *(const float4*)(qrow + ks * 16 + u * 8);
    float4 a1 = *(const float4*)(qrow + ks * 16 + u * 8 + 4);
    bf16x8 q8;
    q8[0] = (short)f2bf(a0.x); q8[1] = (short)f2bf(a0.y);
    q8[2] = (short)f2bf(a0.z); q8[3] = (short)f2bf(a0.w);
    q8[4] = (short)f2bf(a1.x); q8[5] = (short)f2bf(a1.y);
    q8[6] = (short)f2bf(a1.z); q8[7] = (short)f2bf(a1.w);
    qf[ks] = q8;
  }

  f32x16 o0, o1;   // O^T accumulators: h-blocks 0-31, 32-63
#pragma unroll
  for (int i = 0; i < 16; ++i) { o0[i] = 0.f; o1[i] = 0.f; }
  float m_i = -1e30f, l_i = 0.f;
  const float sc2 = 0.125f * 1.44269504088896340736f;  // scale * log2(e)

  // prologue: stage tile 0 -> buf 0, tile 1 -> buf 1
  gload_lds16(KbH + tid * 8, &Ks2[0][tid * 8]);
  gload_lds16(KbH + 2048 + tid * 8, &Ks2[0][2048 + tid * 8]);
  gload_lds16(VbH + tid * 8, &Vt2[0][tid * 8]);
  gload_lds16(VbH + 2048 + tid * 8, &Vt2[0][2048 + tid * 8]);
  gload_lds16(KbH + TILE_ELEMS + tid * 8, &Ks2[1][tid * 8]);
  gload_lds16(KbH + TILE_ELEMS + 2048 + tid * 8, &Ks2[1][2048 + tid * 8]);
  gload_lds16(VbH + TILE_ELEMS + tid * 8, &Vt2[1][tid * 8]);
  gload_lds16(VbH + TILE_ELEMS + 2048 + tid * 8, &Vt2[1][2048 + tid * 8]);
  asm volatile("s_waitcnt vmcnt(4)" ::: "memory");   // tile 0 resident
  __builtin_amdgcn_s_barrier();
  __builtin_amdgcn_sched_barrier(0);

  int cur = 0, stg = 2;
  for (int t = 0; t < NTILES; ++t) {
    // ---- issue prefetch of tile t+2 into buf stg (stays in flight) ----
    {
      const int tl = (t + 2 < NTILES) ? (t + 2) : (NTILES - 1);
      const size_t toff = (size_t)tl * TILE_ELEMS + tid * 8;
      gload_lds16(KbH + toff, &Ks2[stg][tid * 8]);
      gload_lds16(KbH + toff + 2048, &Ks2[stg][2048 + tid * 8]);
      gload_lds16(VbH + toff, &Vt2[stg][tid * 8]);
      gload_lds16(VbH + toff + 2048, &Vt2[stg][2048 + tid * 8]);
    }

    const unsigned short* KsB = Ks2[cur];
    const unsigned short* VtB = Vt2[cur];

    // ---- S^T = K . Q^T ----
    f32x16 s0, s1;
#pragma unroll
    for (int i = 0; i < 16; ++i) { s0[i] = 0.f; s1[i] = 0.f; }
    __builtin_amdgcn_s_setprio(1);
#pragma unroll
    for (int ks = 0; ks < 4; ++ks) {
      const int col8 = 2 * ks + u;
      const int sw = SLOT(col8, ql) * 8;
      const bf16x8 ka0 = *(const bf16x8*)&KsB[ql * 64 + sw];
      const bf16x8 ka1 = *(const bf16x8*)&KsB[(32 + ql) * 64 + sw];
      s0 = __builtin_amdgcn_mfma_f32_32x32x16_bf16(ka0, qf[ks], s0, 0, 0, 0);
      s1 = __builtin_amdgcn_mfma_f32_32x32x16_bf16(ka1, qf[ks], s1, 0, 0, 0);
    }
    __builtin_amdgcn_s_setprio(0);

    // ---- online softmax (tree-max, defer-max T13) ----
    float a8[8];
#pragma unroll
    for (int i = 0; i < 8; ++i)
      a8[i] = fmaxf(fmaxf(s0[i], s0[i + 8]), fmaxf(s1[i], s1[i + 8]));
    float b4a = fmaxf(a8[0], a8[1]), b4b = fmaxf(a8[2], a8[3]);
    float b4c = fmaxf(a8[4], a8[5]), b4d = fmaxf(a8[6], a8[7]);
    float rm = fmaxf(fmaxf(b4a, b4b), fmaxf(b4c, b4d));
    rm = xmax32(rm);
    const float rmx = rm * sc2;
    if (__any(rmx > m_i + 8.f)) {
      float mn = fmaxf(m_i, rmx);
      float so = fast_exp2(m_i - mn);
      m_i = mn;
#pragma unroll
      for (int i = 0; i < 16; ++i) { o0[i] *= so; o1[i] *= so; }
      l_i *= so;
    }

    // ---- P = exp2(S*sc2 - m); in-register redistribution to PV B-frags ----
    float rst[4];
    bf16x8 pf[4];
#pragma unroll
    for (int tq = 0; tq < 4; ++tq) {
      const int be = ((2 * tq) & 3) * 4;       // even-group reg base
      const int bo = ((2 * tq + 1) & 3) * 4;   // odd-group reg base
      float p0[4], p1[4];
#pragma unroll
      for (int r = 0; r < 4; ++r) {
        float se = (tq < 2) ? s0[be + r] : s1[be + r];
        float so_ = (tq < 2) ? s0[bo + r] : s1[bo + r];
        p0[r] = fast_exp2(__builtin_fmaf(se, sc2, -m_i));
        p1[r] = fast_exp2(__builtin_fmaf(so_, sc2, -m_i));
      }
      rst[tq] = ((p0[0] + p0[1]) + (p0[2] + p0[3])) +
                ((p1[0] + p1[1]) + (p1[2] + p1[3]));
      unsigned x0 = cvt_pk_bf16(p0[0], p0[1]);
      unsigned x1 = cvt_pk_bf16(p0[2], p0[3]);
      unsigned y0 = cvt_pk_bf16(p1[0], p1[1]);
      unsigned y1 = cvt_pk_bf16(p1[2], p1[3]);
      pl32swap(x0, y0);
      pl32swap(x1, y1);
      union { unsigned wd[4]; bf16x8 v; } pk;
      pk.wd[0] = x0; pk.wd[1] = x1; pk.wd[2] = y0; pk.wd[3] = y1;
      pf[tq] = pk.v;
    }
    l_i += xsum32((rst[0] + rst[1]) + (rst[2] + rst[3]));

    // ---- O^T += V^T . P^T ----
    __builtin_amdgcn_s_setprio(1);
#pragma unroll
    for (int m = 0; m < 4; ++m) {
      const int col8 = 2 * m + u;
      const int sw = SLOT(col8, ql) * 8;
      const bf16x8 va0 = *(const bf16x8*)&VtB[ql * 64 + sw];
      const bf16x8 va1 = *(const bf16x8*)&VtB[(32 + ql) * 64 + sw];
      o0 = __builtin_amdgcn_mfma_f32_32x32x16_bf16(va0, pf[m], o0, 0, 0, 0);
      o1 = __builtin_amdgcn_mfma_f32_32x32x16_bf16(va1, pf[m], o1, 0, 0, 0);
    }
    __builtin_amdgcn_s_setprio(0);

    // ---- end of tile: t+1 resident (vmcnt<=4), t+2 still in flight ----
    __builtin_amdgcn_sched_barrier(0);
    asm volatile("s_waitcnt vmcnt(4) lgkmcnt(0)" ::: "memory");
    __builtin_amdgcn_s_barrier();
    __builtin_amdgcn_sched_barrier(0);

    cur = (cur == 2) ? 0 : cur + 1;
    stg = (stg == 2) ? 0 : stg + 1;
  }

  // ---- epilogue: O[q][h] = O^T / l ; h = hblk*32 + 8*rg + 4*u + r ----
  const float inv = 1.0f / l_i;
  float* orow = Og + ((size_t)(b * L_ + qr) * C_ + c) * H_;
#pragma unroll
  for (int rg = 0; rg < 4; ++rg) {
    float4 v0, v1;
    v0.x = o0[rg * 4 + 0] * inv; v0.y = o0[rg * 4 + 1] * inv;
    v0.z = o0[rg * 4 + 2] * inv; v0.w = o0[rg * 4 + 3] * inv;
    v1.x = o1[rg * 4 + 0] * inv; v1.y = o1[rg * 4 + 1] * inv;
    v1.z = o1[rg * 4 + 2] * inv; v1.w = o1[rg * 4 + 3] * inv;
    *(float4*)(orow + 8 * rg + 4 * u) = v0;
    *(float4*)(orow + 32 + 8 * rg + 4 * u) = v1;
  }
}

extern "C" void kernel_launch(void* const* d_in, const int* in_sizes, int n_in,
                              void* d_out, int out_size, void* d_ws, size_t ws_size,
                              hipStream_t stream) {
  const float* Qg = (const float*)d_in[0];
  const float* Kg = (const float*)d_in[1];
  const float* Vg = (const float*)d_in[2];
  float* Og = (float*)d_out;

  unsigned short* Kb = (unsigned short*)d_ws;
  unsigned short* Vb = Kb + (size_t)TENSOR_ELEMS;

  prepack_kernel<<<4096, 256, 0, stream>>>(Kg, Vg, Kb, Vb);

  dim3 grid(NHEADS * (L_ / QBLK));   // 512 blocks, 2 per CU
  dim3 block(NTHREADS);
  attn_fwd_kernel<<<grid, block, 0, stream>>>(Qg, Kb, Vb, Og);
}